// Round 7
// baseline (45.926 us; speedup 1.0000x reference)
//
#include <hip/hip_runtime.h>
#include <math.h>

#define NB 16
#define NA 19200
#define NT 50
#define NC 80
#define LAMBDA_COORD 5.0f
#define F_EPS 1e-6f

// K1: direct argmax. block = (b, group of TPG targets), all anchors per block.
#define TPG 5
#define NGRP (NT / TPG)          // 10
#define K1_BLOCKS (NB * NGRP)    // 160
#define K1_THREADS 1024
#define K1_WAVES (K1_THREADS / 64)

// K2: unified loss, few big blocks, grid-stride.
#define K2_BLOCKS 64
#define K2_THREADS 1024
#define K2_GSTRIDE (K2_BLOCKS * K2_THREADS)   // 65536

// ws layout:
// [0    .. 256)    float part[64]
// [256  .. 3456)   int   best_idx[800]

__device__ __forceinline__ float bce_logits(float x, float z) {
    return fmaxf(x, 0.0f) - x * z + log1pf(expf(-fabsf(x)));
}

// ------- K1: per-(b, target-group) argmax over ALL anchors -------
__global__ __launch_bounds__(1024) void argmax_direct_kernel(
        const float4* __restrict__ pb,
        const float4* __restrict__ tb,
        int* __restrict__ best_idx) {
    const int b   = blockIdx.x / NGRP;
    const int g   = blockIdx.x % NGRP;
    const int tid = threadIdx.x;

    float4 t4[TPG];
    float  ta[TPG];
    #pragma unroll
    for (int i = 0; i < TPG; ++i) {
        t4[i] = tb[b * NT + g * TPG + i];
        ta[i] = (t4[i].z - t4[i].x) * (t4[i].w - t4[i].y);
    }

    float best[TPG];
    int   bidx[TPG];
    #pragma unroll
    for (int i = 0; i < TPG; ++i) { best[i] = -1.0f; bidx[i] = NA; }

    for (int a = tid; a < NA; a += K1_THREADS) {       // ascending -> first-idx ties kept
        float4 p = pb[(size_t)b * NA + a];
        float area1 = (p.z - p.x) * (p.w - p.y);
        #pragma unroll
        for (int i = 0; i < TPG; ++i) {
            float ix1 = fmaxf(p.x, t4[i].x), iy1 = fmaxf(p.y, t4[i].y);
            float ix2 = fminf(p.z, t4[i].z), iy2 = fminf(p.w, t4[i].w);
            float inter = fmaxf(ix2 - ix1, 0.0f) * fmaxf(iy2 - iy1, 0.0f);
            float iou = inter / (area1 + ta[i] - inter + F_EPS);
            if (iou > best[i]) { best[i] = iou; bidx[i] = a; }
        }
    }

    const int wave = tid >> 6;
    const int lane = tid & 63;
    __shared__ float swv[K1_WAVES][TPG];
    __shared__ int   swi[K1_WAVES][TPG];
    #pragma unroll
    for (int i = 0; i < TPG; ++i) {
        float v = best[i];
        int   ix = bidx[i];
        #pragma unroll
        for (int m = 1; m < 64; m <<= 1) {
            float ov = __shfl_xor(v, m);
            int   oi = __shfl_xor(ix, m);
            if (ov > v || (ov == v && oi < ix)) { v = ov; ix = oi; }
        }
        if (lane == 0) { swv[wave][i] = v; swi[wave][i] = ix; }
    }
    __syncthreads();

    if (tid < TPG) {
        float v = swv[0][tid];
        int   ix = swi[0][tid];
        #pragma unroll
        for (int w = 1; w < K1_WAVES; ++w) {
            float ov = swv[w][tid];
            int   oi = swi[w][tid];
            if (ov > v || (ov == v && oi < ix)) { v = ov; ix = oi; }
        }
        best_idx[b * NT + g * TPG + tid] = ix;
    }
}

// ------- K2: all three loss components, grid-stride, weighted per-thread acc -------
__global__ __launch_bounds__(1024) void loss_kernel(
        const float* __restrict__ pb,
        const float* __restrict__ pc,
        const float* __restrict__ pcls,
        const float* __restrict__ tb,
        const int* __restrict__ tl,
        const int* __restrict__ best_idx,
        float* __restrict__ part) {
    const float W_OBJ = 1.0f / (float)(NB * NA);
    const float W_BOX = LAMBDA_COORD / (float)(NB * NT);
    const float W_CLS = 1.0f / (float)(NB * NT * NC);

    __shared__ int sbi[NB * NT];
    for (int i = threadIdx.x; i < NB * NT; i += K2_THREADS)
        sbi[i] = best_idx[i];
    __syncthreads();

    const int gtid = blockIdx.x * K2_THREADS + threadIdx.x;
    float s = 0.0f;

    // ---- objectness BCE over (b,a) ----
    for (int i = gtid; i < NB * NA; i += K2_GSTRIDE) {
        const int b = i / NA;
        const int a = i - b * NA;
        const int* bi = sbi + b * NT;
        float z = 0.0f;
        #pragma unroll
        for (int t = 0; t < NT; ++t)
            if (bi[t] == a) z = 1.0f;
        s += W_OBJ * bce_logits(pc[i], z);
    }

    // ---- class BCE over (b,t,c) ----
    for (int i = gtid; i < NB * NT * NC; i += K2_GSTRIDE) {
        const int bt = i / NC;
        const int c  = i - bt * NC;
        const int b  = bt / NT;
        float x = pcls[((size_t)b * NA + sbi[bt]) * NC + c];
        float z = (tl[bt] == c) ? 1.0f : 0.0f;
        s += W_CLS * bce_logits(x, z);
    }

    // ---- CIoU over (b,t) ----
    for (int bt = gtid; bt < NB * NT; bt += K2_GSTRIDE) {
        const int b  = bt / NT;
        const int bi = sbi[bt];
        const float* p  = pb + ((size_t)b * NA + bi) * 4;
        const float* tg = tb + (size_t)bt * 4;
        float b1x1 = p[0],  b1y1 = p[1],  b1x2 = p[2],  b1y2 = p[3];
        float b2x1 = tg[0], b2y1 = tg[1], b2x2 = tg[2], b2y2 = tg[3];

        float area1 = (b1x2 - b1x1) * (b1y2 - b1y1);
        float area2 = (b2x2 - b2x1) * (b2y2 - b2y1);
        float iw = fmaxf(fminf(b1x2, b2x2) - fmaxf(b1x1, b2x1), 0.0f);
        float ih = fmaxf(fminf(b1y2, b2y2) - fmaxf(b1y1, b2y1), 0.0f);
        float inter = iw * ih;
        float iou = inter / (area1 + area2 - inter + F_EPS);

        float cdx = fmaxf(b1x2, b2x2) - fminf(b1x1, b2x1);
        float cdy = fmaxf(b1y2, b2y2) - fminf(b1y1, b2y1);
        float c_diag = cdx * cdx + cdy * cdy;

        float cx = (b1x1 + b1x2 - b2x1 - b2x2) * 0.5f;
        float cy = (b1y1 + b1y2 - b2y1 - b2y2) * 0.5f;
        float center_dist = cx * cx + cy * cy;

        float w1 = b1x2 - b1x1, h1 = b1y2 - b1y1;
        float w2 = b2x2 - b2x1, h2 = b2y2 - b2y1;
        float dat = atanf(w2 / h2) - atanf(w1 / h1);
        float vv = (float)(4.0 / (M_PI * M_PI)) * dat * dat;
        float alpha = vv / (1.0f - iou + vv + F_EPS);
        float ciou = iou - center_dist / c_diag - alpha * vv;
        s += W_BOX * (1.0f - ciou);
    }

    // ---- block reduce ----
    __shared__ float sred[K2_THREADS];
    sred[threadIdx.x] = s;
    __syncthreads();
    for (int st = K2_THREADS / 2; st > 0; st >>= 1) {
        if ((int)threadIdx.x < st) sred[threadIdx.x] += sred[threadIdx.x + st];
        __syncthreads();
    }
    if (threadIdx.x == 0) part[blockIdx.x] = sred[0];
}

// ------- K3: sum 64 partials -------
__global__ __launch_bounds__(64) void final_kernel(
        const float* __restrict__ part, float* __restrict__ out) {
    float s = part[threadIdx.x];
    #pragma unroll
    for (int m = 32; m > 0; m >>= 1) s += __shfl_down(s, m);
    if (threadIdx.x == 0) out[0] = s;
}

extern "C" void kernel_launch(void* const* d_in, const int* in_sizes, int n_in,
                              void* d_out, int out_size, void* d_ws, size_t ws_size,
                              hipStream_t stream) {
    const float* pb   = (const float*)d_in[0];   // (B,A,4)
    const float* pc   = (const float*)d_in[1];   // (B,A,1)
    const float* pcls = (const float*)d_in[2];   // (B,A,C)
    const float* tb   = (const float*)d_in[3];   // (B,T,4)
    const int*   tl   = (const int*)d_in[4];     // (B,T)

    char* ws = (char*)d_ws;
    float* part     = (float*)ws;            // 64 floats
    int*   best_idx = (int*)(ws + 256);      // 800 ints

    argmax_direct_kernel<<<K1_BLOCKS, K1_THREADS, 0, stream>>>(
        (const float4*)pb, (const float4*)tb, best_idx);
    loss_kernel<<<K2_BLOCKS, K2_THREADS, 0, stream>>>(
        pb, pc, pcls, tb, tl, best_idx, part);
    final_kernel<<<1, 64, 0, stream>>>(part, (float*)d_out);
}